// Round 7
// baseline (134.048 us; speedup 1.0000x reference)
//
#include <hip/hip_runtime.h>
#include <hip/hip_bf16.h>
#include <stdint.h>

#define NN 4096
#define DD 1024
// data scaled by 64 per matrix -> products x4096; logits = dot * 10
#define SCL (10.0f / 4096.0f)

typedef float f32x16 __attribute__((ext_vector_type(16)));
typedef int   i32x4  __attribute__((ext_vector_type(4)));
typedef int   i32x8  __attribute__((ext_vector_type(8)));

__device__ __forceinline__ void gload_lds16(const void* g, void* l) {
  __builtin_amdgcn_global_load_lds(
      (const __attribute__((address_space(1))) void*)g,
      (__attribute__((address_space(3))) void*)l, 16, 0, 0);
}

// ---------- kernel 1: row-L2-normalize -> fp8 e4m3 (x64), exact fp32 diagonal ----------
__global__ __launch_bounds__(256) void nrm_kernel(
    const float* __restrict__ e1, const float* __restrict__ e2,
    uint32_t* __restrict__ e1q, uint32_t* __restrict__ e2q,
    float* __restrict__ log_diag, float* __restrict__ exp_diag,
    float* __restrict__ row_sum, float* __restrict__ col_sum)
{
  const int row  = blockIdx.x;
  const int tid  = threadIdx.x;
  const int lane = tid & 63;
  const int wave = tid >> 6;
  const int64_t base = (int64_t)row * DD;

  const float4 v1 = *reinterpret_cast<const float4*>(e1 + base + tid * 4);
  const float4 v2 = *reinterpret_cast<const float4*>(e2 + base + tid * 4);

  float ss1 = v1.x*v1.x + v1.y*v1.y + v1.z*v1.z + v1.w*v1.w;
  float ss2 = v2.x*v2.x + v2.y*v2.y + v2.z*v2.z + v2.w*v2.w;
  float d12 = v1.x*v2.x + v1.y*v2.y + v1.z*v2.z + v1.w*v2.w;

  #pragma unroll
  for (int off = 1; off < 64; off <<= 1) {
    ss1 += __shfl_xor(ss1, off);
    ss2 += __shfl_xor(ss2, off);
    d12 += __shfl_xor(d12, off);
  }

  __shared__ float red[3][4];
  if (lane == 0) { red[0][wave] = ss1; red[1][wave] = ss2; red[2][wave] = d12; }
  __syncthreads();
  ss1 = red[0][0] + red[0][1] + red[0][2] + red[0][3];
  ss2 = red[1][0] + red[1][1] + red[1][2] + red[1][3];
  d12 = red[2][0] + red[2][1] + red[2][2] + red[2][3];

  const float inv1 = 1.0f / fmaxf(sqrtf(ss1), 1e-12f);
  const float inv2 = 1.0f / fmaxf(sqrtf(ss2), 1e-12f);

  if (tid == 0) {
    const float ld = d12 * inv1 * inv2 * 10.0f;
    log_diag[row] = ld;
    exp_diag[row] = __expf(ld);
    row_sum[row] = 0.0f;
    col_sum[row] = 0.0f;
  }

  const float s1 = inv1 * 64.0f;
  const float s2 = inv2 * 64.0f;
  int u1 = __builtin_amdgcn_cvt_pk_fp8_f32(v1.x * s1, v1.y * s1, 0, false);
  u1     = __builtin_amdgcn_cvt_pk_fp8_f32(v1.z * s1, v1.w * s1, u1, true);
  int u2 = __builtin_amdgcn_cvt_pk_fp8_f32(v2.x * s2, v2.y * s2, 0, false);
  u2     = __builtin_amdgcn_cvt_pk_fp8_f32(v2.z * s2, v2.w * s2, u2, true);
  e1q[row * (DD / 4) + tid] = (uint32_t)u1;
  e2q[row * (DD / 4) + tid] = (uint32_t)u2;
}

// ---------- kernel 2: fused MX-fp8 GEMM 256x128 tile, 2 blocks/CU ----------
// 8 waves (4M x 2N), wave tile 64x64, BK=64, mfma_scale_f32_32x32x64_f8f6f4
// with all scale bytes = 0x7F (1.0) -> bit-identical to plain fp8 GEMM but
// at 2.13x MFMA rate. LDS 48 KiB dbuf, staging identical to R6 (verified);
// read side: 32B fragment = 2 x b128 at chunk ^ ((row>>1)&3) (bank floor).
__global__ __launch_bounds__(512, 4) void gemm_kernel(
    const uint8_t* __restrict__ A,   // e1q [NN][DD] fp8 bits (x64)
    const uint8_t* __restrict__ B,   // e2q [NN][DD] fp8 bits (x64)
    float* __restrict__ row_sum, float* __restrict__ col_sum)
{
  __shared__ __align__(16) uint8_t lds_a[2][256][64];   // 32 KiB
  __shared__ __align__(16) uint8_t lds_b[2][128][64];   // 16 KiB

  const int tid  = threadIdx.x;
  const int lane = tid & 63;
  const int wave = tid >> 6;          // 0..7
  const int wm = wave >> 1;           // 0..3 : rows [wm*64, +64)
  const int wn = wave & 1;            // 0..1 : cols [wn*64, +64)

  // XCD swizzle: grid 16x32 tiles; each XCD owns a 4x16 rectangle (3 MB < 4 MB L2)
  const int bid = blockIdx.x;
  const int xcd = bid & 7;
  const int k   = bid >> 3;           // 0..63
  const int brow = ((xcd >> 1) * 4 + (k >> 4)) * 256;
  const int bcol = ((xcd & 1) * 16 + (k & 15)) * 128;

  // fragment geometry (32x32x64): row = lane&31, k = (lane>>5)*32 + e
  const int r32 = lane & 31;
  const int h   = lane >> 5;
  const int cx  = (r32 >> 1) & 3;               // row-derived 16B-chunk XOR
  const int ch0 = ((h * 2)     ^ cx) * 16;      // byte offset, first 16B of frag
  const int ch1 = ((h * 2 + 1) ^ cx) * 16;      // second 16B

  // staging: lane l writes 16B chunk (l&3) of row (l>>2); source chunk
  // pre-swizzled by ((row>>1)&3) = ((l>>3)&3)  [same involution as read side]
  const int s_chunk = ((lane & 3) ^ ((lane >> 3) & 3)) * 16;
  const uint8_t* a_src0 = A + (int64_t)(brow + wave * 32 + (lane >> 2)) * DD + s_chunk;
  const uint8_t* a_src1 = a_src0 + 16 * DD;
  const uint8_t* b_src  = B + (int64_t)(bcol + wave * 16 + (lane >> 2)) * DD + s_chunk;

  f32x16 acc[2][2] = {};

#define STAGE(n, kc)                                          \
  gload_lds16(a_src0 + (kc), &lds_a[n][wave * 32][0]);        \
  gload_lds16(a_src1 + (kc), &lds_a[n][wave * 32 + 16][0]);   \
  gload_lds16(b_src  + (kc), &lds_b[n][wave * 16][0]);

#define TILE(c, PF, KC)                                                        \
  {                                                                            \
    asm volatile("s_waitcnt vmcnt(0)" ::: "memory");                           \
    __builtin_amdgcn_s_barrier();                                              \
    i32x8 av[2], bv[2];                                                        \
    _Pragma("unroll")                                                          \
    for (int i = 0; i < 2; ++i) {                                              \
      const i32x4 lo = *reinterpret_cast<const i32x4*>(                        \
          &lds_a[c][wm * 64 + i * 32 + r32][ch0]);                             \
      const i32x4 hi = *reinterpret_cast<const i32x4*>(                        \
          &lds_a[c][wm * 64 + i * 32 + r32][ch1]);                             \
      av[i] = __builtin_shufflevector(lo, hi, 0, 1, 2, 3, 4, 5, 6, 7);         \
    }                                                                          \
    _Pragma("unroll")                                                          \
    for (int j = 0; j < 2; ++j) {                                              \
      const i32x4 lo = *reinterpret_cast<const i32x4*>(                        \
          &lds_b[c][wn * 64 + j * 32 + r32][ch0]);                             \
      const i32x4 hi = *reinterpret_cast<const i32x4*>(                        \
          &lds_b[c][wn * 64 + j * 32 + r32][ch1]);                             \
      bv[j] = __builtin_shufflevector(lo, hi, 0, 1, 2, 3, 4, 5, 6, 7);         \
    }                                                                          \
    if (PF) { STAGE((c) ^ 1, KC) }                                             \
    __builtin_amdgcn_s_setprio(1);                                             \
    _Pragma("unroll")                                                          \
    for (int i = 0; i < 2; ++i) {                                              \
      _Pragma("unroll")                                                        \
      for (int j = 0; j < 2; ++j)                                              \
        acc[i][j] = __builtin_amdgcn_mfma_scale_f32_32x32x64_f8f6f4(           \
            av[i], bv[j], acc[i][j], 0, 0,                                     \
            0, 0x7F7F7F7F, 0, 0x7F7F7F7F);                                     \
    }                                                                          \
    __builtin_amdgcn_s_setprio(0);                                             \
  }

  // prologue: stage tile 0 into slot 0
  STAGE(0, 0)

  #pragma unroll 2
  for (int t = 0; t < DD / 64; ++t) {
    TILE(t & 1, t < DD / 64 - 1, (t + 1) * 64)
  }
#undef TILE
#undef STAGE

  // ---- fused epilogue: v = exp(SCL*acc); row & col partial sums ----
  // 32x32 C/D layout: col = lane&31, row = (r&3) + 8*(r>>2) + 4*(lane>>5)
  float colp[2] = {0.0f, 0.0f};

  #pragma unroll
  for (int mi = 0; mi < 2; ++mi) {
    float rp[16];
    #pragma unroll
    for (int r = 0; r < 16; ++r) rp[r] = 0.0f;
    #pragma unroll
    for (int ni = 0; ni < 2; ++ni) {
      #pragma unroll
      for (int r = 0; r < 16; ++r) {
        const float v = __expf(acc[mi][ni][r] * SCL);
        rp[r]    += v;
        colp[ni] += v;
      }
    }
    // row sums: reduce across the 32 col-lanes of this half
    #pragma unroll
    for (int r = 0; r < 16; ++r) {
      float rr = rp[r];
      rr += __shfl_xor(rr, 1);
      rr += __shfl_xor(rr, 2);
      rr += __shfl_xor(rr, 4);
      rr += __shfl_xor(rr, 8);
      rr += __shfl_xor(rr, 16);
      if (r32 == 0) {
        atomicAdd(&row_sum[brow + wm * 64 + mi * 32 + (r & 3) + 8 * (r >> 2) + 4 * h], rr);
      }
    }
  }
  // col sums: combine the two 32-lane halves (same col, disjoint rows)
  #pragma unroll
  for (int ni = 0; ni < 2; ++ni) {
    float cc = colp[ni];
    cc += __shfl_xor(cc, 32);
    if (h == 0) {
      atomicAdd(&col_sum[bcol + wn * 64 + ni * 32 + r32], cc);
    }
  }
}

// ---------- kernel 3: final scalar reduction (block 0 -> rows, block 1 -> cols) ----------
__global__ __launch_bounds__(1024) void fin_kernel(
    const float* __restrict__ row_sum, const float* __restrict__ col_sum,
    const float* __restrict__ log_diag, const float* __restrict__ exp_diag,
    float* __restrict__ out)
{
  const int tid  = threadIdx.x;
  const int lane = tid & 63;
  const int wave = tid >> 6;
  const float* sums = (blockIdx.x == 0) ? row_sum : col_sum;
  float a = 0.0f;
  #pragma unroll
  for (int kk = 0; kk < NN / 1024; ++kk) {
    const int i = tid + kk * 1024;
    a += logf(sums[i] - exp_diag[i]) - log_diag[i];
  }
  #pragma unroll
  for (int off = 1; off < 64; off <<= 1) a += __shfl_xor(a, off);
  __shared__ float r0[16];
  if (lane == 0) r0[wave] = a;
  __syncthreads();
  if (tid == 0) {
    float s = 0.0f;
    #pragma unroll
    for (int w = 0; w < 16; ++w) s += r0[w];
    out[blockIdx.x] = s;
  }
}

extern "C" void kernel_launch(void* const* d_in, const int* in_sizes, int n_in,
                              void* d_out, int out_size, void* d_ws, size_t ws_size,
                              hipStream_t stream) {
  const float* e1 = (const float*)d_in[0];
  const float* e2 = (const float*)d_in[1];
  float* out = (float*)d_out;

  char* ws = (char*)d_ws;
  uint32_t* e1q = (uint32_t*)ws;                                 // 4 MB (fp8)
  uint32_t* e2q = (uint32_t*)(ws + (size_t)NN * DD);             // 4 MB (fp8)
  float* log_diag = (float*)(ws + (size_t)NN * DD * 2);          // 16 KB
  float* exp_diag = log_diag + NN;                               // 16 KB
  float* row_sum  = exp_diag + NN;                               // 16 KB
  float* col_sum  = row_sum + NN;                                // 16 KB

  nrm_kernel<<<NN, 256, 0, stream>>>(e1, e2, e1q, e2q, log_diag, exp_diag,
                                     row_sum, col_sum);
  gemm_kernel<<<512, 512, 0, stream>>>((const uint8_t*)e1q, (const uint8_t*)e2q,
                                       row_sum, col_sum);
  fin_kernel<<<2, 1024, 0, stream>>>(row_sum, col_sum, log_diag, exp_diag, out);
}

// Round 8
// 132.865 us; speedup vs baseline: 1.0089x; 1.0089x over previous
//
#include <hip/hip_runtime.h>
#include <hip/hip_bf16.h>
#include <stdint.h>

#define NN 4096
#define DD 1024
// data scaled by 64 per matrix -> products x4096; logits = dot * 10
#define SCL (10.0f / 4096.0f)

typedef float f32x16 __attribute__((ext_vector_type(16)));
typedef int   i32x4  __attribute__((ext_vector_type(4)));
typedef int   i32x8  __attribute__((ext_vector_type(8)));

__device__ __forceinline__ void gload_lds16(const void* g, void* l) {
  __builtin_amdgcn_global_load_lds(
      (const __attribute__((address_space(1))) void*)g,
      (__attribute__((address_space(3))) void*)l, 16, 0, 0);
}

// ---------- kernel 1: row-L2-normalize -> fp8 e4m3 (x64), exact fp32 diagonal ----------
__global__ __launch_bounds__(256) void nrm_kernel(
    const float* __restrict__ e1, const float* __restrict__ e2,
    uint32_t* __restrict__ e1q, uint32_t* __restrict__ e2q,
    float* __restrict__ log_diag, float* __restrict__ exp_diag,
    float* __restrict__ row_sum, float* __restrict__ col_sum)
{
  const int row  = blockIdx.x;
  const int tid  = threadIdx.x;
  const int lane = tid & 63;
  const int wave = tid >> 6;
  const int64_t base = (int64_t)row * DD;

  const float4 v1 = *reinterpret_cast<const float4*>(e1 + base + tid * 4);
  const float4 v2 = *reinterpret_cast<const float4*>(e2 + base + tid * 4);

  float ss1 = v1.x*v1.x + v1.y*v1.y + v1.z*v1.z + v1.w*v1.w;
  float ss2 = v2.x*v2.x + v2.y*v2.y + v2.z*v2.z + v2.w*v2.w;
  float d12 = v1.x*v2.x + v1.y*v2.y + v1.z*v2.z + v1.w*v2.w;

  #pragma unroll
  for (int off = 1; off < 64; off <<= 1) {
    ss1 += __shfl_xor(ss1, off);
    ss2 += __shfl_xor(ss2, off);
    d12 += __shfl_xor(d12, off);
  }

  __shared__ float red[3][4];
  if (lane == 0) { red[0][wave] = ss1; red[1][wave] = ss2; red[2][wave] = d12; }
  __syncthreads();
  ss1 = red[0][0] + red[0][1] + red[0][2] + red[0][3];
  ss2 = red[1][0] + red[1][1] + red[1][2] + red[1][3];
  d12 = red[2][0] + red[2][1] + red[2][2] + red[2][3];

  const float inv1 = 1.0f / fmaxf(sqrtf(ss1), 1e-12f);
  const float inv2 = 1.0f / fmaxf(sqrtf(ss2), 1e-12f);

  if (tid == 0) {
    const float ld = d12 * inv1 * inv2 * 10.0f;
    log_diag[row] = ld;
    exp_diag[row] = __expf(ld);
    row_sum[row] = 0.0f;
    col_sum[row] = 0.0f;
  }

  const float s1 = inv1 * 64.0f;
  const float s2 = inv2 * 64.0f;
  int u1 = __builtin_amdgcn_cvt_pk_fp8_f32(v1.x * s1, v1.y * s1, 0, false);
  u1     = __builtin_amdgcn_cvt_pk_fp8_f32(v1.z * s1, v1.w * s1, u1, true);
  int u2 = __builtin_amdgcn_cvt_pk_fp8_f32(v2.x * s2, v2.y * s2, 0, false);
  u2     = __builtin_amdgcn_cvt_pk_fp8_f32(v2.z * s2, v2.w * s2, u2, true);
  e1q[row * (DD / 4) + tid] = (uint32_t)u1;
  e2q[row * (DD / 4) + tid] = (uint32_t)u2;
}

// ---------- kernel 2: fused MX-fp8 GEMM 256x128 tile, 2 blocks/CU ----------
// Identical math/layout to R7 (verified absmax 0.0) but ALL wide-vector locals
// are named scalars (not arrays) so they promote to registers instead of
// scratch (R7: f32x16 acc[2][2] -> localMem, 300 MB scratch traffic, 2.6x slow).
__global__ __launch_bounds__(512, 4) void gemm_kernel(
    const uint8_t* __restrict__ A,   // e1q [NN][DD] fp8 bits (x64)
    const uint8_t* __restrict__ B,   // e2q [NN][DD] fp8 bits (x64)
    float* __restrict__ row_sum, float* __restrict__ col_sum)
{
  __shared__ __align__(16) uint8_t lds_a[2][256][64];   // 32 KiB
  __shared__ __align__(16) uint8_t lds_b[2][128][64];   // 16 KiB

  const int tid  = threadIdx.x;
  const int lane = tid & 63;
  const int wave = tid >> 6;          // 0..7
  const int wm = wave >> 1;           // 0..3 : rows [wm*64, +64)
  const int wn = wave & 1;            // 0..1 : cols [wn*64, +64)

  // XCD swizzle: grid 16x32 tiles; each XCD owns a 4x16 rectangle (3 MB < 4 MB L2)
  const int bid = blockIdx.x;
  const int xcd = bid & 7;
  const int k   = bid >> 3;           // 0..63
  const int brow = ((xcd >> 1) * 4 + (k >> 4)) * 256;
  const int bcol = ((xcd & 1) * 16 + (k & 15)) * 128;

  // fragment geometry (32x32x64): row = lane&31, k = (lane>>5)*32 + e
  const int r32 = lane & 31;
  const int h   = lane >> 5;
  const int cx  = (r32 >> 1) & 3;               // row-derived 16B-chunk XOR
  const int ch0 = ((h * 2)     ^ cx) * 16;      // byte offset, first 16B of frag
  const int ch1 = ((h * 2 + 1) ^ cx) * 16;      // second 16B

  // staging: lane l writes 16B chunk (l&3) of row (l>>2); source chunk
  // pre-swizzled by ((row>>1)&3) = ((l>>3)&3)  [same involution as read side]
  const int s_chunk = ((lane & 3) ^ ((lane >> 3) & 3)) * 16;
  const uint8_t* a_src0 = A + (int64_t)(brow + wave * 32 + (lane >> 2)) * DD + s_chunk;
  const uint8_t* a_src1 = a_src0 + 16 * DD;
  const uint8_t* b_src  = B + (int64_t)(bcol + wave * 16 + (lane >> 2)) * DD + s_chunk;

  f32x16 acc00 = {}, acc01 = {}, acc10 = {}, acc11 = {};

#define STAGE(n, kc)                                          \
  gload_lds16(a_src0 + (kc), &lds_a[n][wave * 32][0]);        \
  gload_lds16(a_src1 + (kc), &lds_a[n][wave * 32 + 16][0]);   \
  gload_lds16(b_src  + (kc), &lds_b[n][wave * 16][0]);

#define LOADFRAG(dst, ldsbuf, c, rbase)                                        \
  {                                                                            \
    const i32x4 lo_ = *reinterpret_cast<const i32x4*>(&ldsbuf[c][rbase][ch0]); \
    const i32x4 hi_ = *reinterpret_cast<const i32x4*>(&ldsbuf[c][rbase][ch1]); \
    dst = __builtin_shufflevector(lo_, hi_, 0, 1, 2, 3, 4, 5, 6, 7);           \
  }

#define TILE(c, PF, KC)                                                        \
  {                                                                            \
    asm volatile("s_waitcnt vmcnt(0)" ::: "memory");                           \
    __builtin_amdgcn_s_barrier();                                              \
    i32x8 av0, av1, bv0, bv1;                                                  \
    LOADFRAG(av0, lds_a, c, wm * 64 + r32)                                     \
    LOADFRAG(av1, lds_a, c, wm * 64 + 32 + r32)                                \
    LOADFRAG(bv0, lds_b, c, wn * 64 + r32)                                     \
    LOADFRAG(bv1, lds_b, c, wn * 64 + 32 + r32)                                \
    if (PF) { STAGE((c) ^ 1, KC) }                                             \
    __builtin_amdgcn_s_setprio(1);                                             \
    acc00 = __builtin_amdgcn_mfma_scale_f32_32x32x64_f8f6f4(                   \
        av0, bv0, acc00, 0, 0, 0, 0x7F7F7F7F, 0, 0x7F7F7F7F);                  \
    acc01 = __builtin_amdgcn_mfma_scale_f32_32x32x64_f8f6f4(                   \
        av0, bv1, acc01, 0, 0, 0, 0x7F7F7F7F, 0, 0x7F7F7F7F);                  \
    acc10 = __builtin_amdgcn_mfma_scale_f32_32x32x64_f8f6f4(                   \
        av1, bv0, acc10, 0, 0, 0, 0x7F7F7F7F, 0, 0x7F7F7F7F);                  \
    acc11 = __builtin_amdgcn_mfma_scale_f32_32x32x64_f8f6f4(                   \
        av1, bv1, acc11, 0, 0, 0, 0x7F7F7F7F, 0, 0x7F7F7F7F);                  \
    __builtin_amdgcn_s_setprio(0);                                             \
  }

  // prologue: stage tile 0 into slot 0
  STAGE(0, 0)

  #pragma unroll 2
  for (int t = 0; t < DD / 64; ++t) {
    TILE(t & 1, t < DD / 64 - 1, (t + 1) * 64)
  }
#undef TILE
#undef LOADFRAG
#undef STAGE

  // ---- fused epilogue: v = exp(SCL*acc); row & col partial sums ----
  // 32x32 C/D layout: col = lane&31, row = (r&3) + 8*(r>>2) + 4*(lane>>5)
  float colp0 = 0.0f, colp1 = 0.0f;

#define ROWSUM(ACCL, ACCR, MI)                                                 \
  {                                                                            \
    _Pragma("unroll")                                                          \
    for (int r = 0; r < 16; ++r) {                                             \
      const float vL = __expf((ACCL)[r] * SCL);                                \
      const float vR = __expf((ACCR)[r] * SCL);                                \
      colp0 += vL;                                                             \
      colp1 += vR;                                                             \
      float rr = vL + vR;                                                      \
      rr += __shfl_xor(rr, 1);                                                 \
      rr += __shfl_xor(rr, 2);                                                 \
      rr += __shfl_xor(rr, 4);                                                 \
      rr += __shfl_xor(rr, 8);                                                 \
      rr += __shfl_xor(rr, 16);                                                \
      if (r32 == 0) {                                                          \
        atomicAdd(&row_sum[brow + wm * 64 + (MI) * 32 +                        \
                           (r & 3) + 8 * (r >> 2) + 4 * h], rr);               \
      }                                                                        \
    }                                                                          \
  }

  ROWSUM(acc00, acc01, 0)
  ROWSUM(acc10, acc11, 1)
#undef ROWSUM

  // col sums: combine the two 32-lane halves (same col, disjoint rows)
  {
    float cc = colp0;
    cc += __shfl_xor(cc, 32);
    if (h == 0) atomicAdd(&col_sum[bcol + wn * 64 + r32], cc);
  }
  {
    float cc = colp1;
    cc += __shfl_xor(cc, 32);
    if (h == 0) atomicAdd(&col_sum[bcol + wn * 64 + 32 + r32], cc);
  }
}

// ---------- kernel 3: final scalar reduction (block 0 -> rows, block 1 -> cols) ----------
__global__ __launch_bounds__(1024) void fin_kernel(
    const float* __restrict__ row_sum, const float* __restrict__ col_sum,
    const float* __restrict__ log_diag, const float* __restrict__ exp_diag,
    float* __restrict__ out)
{
  const int tid  = threadIdx.x;
  const int lane = tid & 63;
  const int wave = tid >> 6;
  const float* sums = (blockIdx.x == 0) ? row_sum : col_sum;
  float a = 0.0f;
  #pragma unroll
  for (int kk = 0; kk < NN / 1024; ++kk) {
    const int i = tid + kk * 1024;
    a += logf(sums[i] - exp_diag[i]) - log_diag[i];
  }
  #pragma unroll
  for (int off = 1; off < 64; off <<= 1) a += __shfl_xor(a, off);
  __shared__ float r0[16];
  if (lane == 0) r0[wave] = a;
  __syncthreads();
  if (tid == 0) {
    float s = 0.0f;
    #pragma unroll
    for (int w = 0; w < 16; ++w) s += r0[w];
    out[blockIdx.x] = s;
  }
}

extern "C" void kernel_launch(void* const* d_in, const int* in_sizes, int n_in,
                              void* d_out, int out_size, void* d_ws, size_t ws_size,
                              hipStream_t stream) {
  const float* e1 = (const float*)d_in[0];
  const float* e2 = (const float*)d_in[1];
  float* out = (float*)d_out;

  char* ws = (char*)d_ws;
  uint32_t* e1q = (uint32_t*)ws;                                 // 4 MB (fp8)
  uint32_t* e2q = (uint32_t*)(ws + (size_t)NN * DD);             // 4 MB (fp8)
  float* log_diag = (float*)(ws + (size_t)NN * DD * 2);          // 16 KB
  float* exp_diag = log_diag + NN;                               // 16 KB
  float* row_sum  = exp_diag + NN;                               // 16 KB
  float* col_sum  = row_sum + NN;                                // 16 KB

  nrm_kernel<<<NN, 256, 0, stream>>>(e1, e2, e1q, e2q, log_diag, exp_diag,
                                     row_sum, col_sum);
  gemm_kernel<<<512, 512, 0, stream>>>((const uint8_t*)e1q, (const uint8_t*)e2q,
                                       row_sum, col_sum);
  fin_kernel<<<2, 1024, 0, stream>>>(row_sum, col_sum, log_diag, exp_diag, out);
}

// Round 9
// 72.531 us; speedup vs baseline: 1.8482x; 1.8318x over previous
//
#include <hip/hip_runtime.h>
#include <hip/hip_bf16.h>
#include <stdint.h>

#define NN 4096
#define DD 1024
// data scaled by 64 per matrix -> products x4096; logits = dot * 10
#define SCL (10.0f / 4096.0f)

typedef float f32x16 __attribute__((ext_vector_type(16)));
typedef int   i32x4  __attribute__((ext_vector_type(4)));
typedef int   i32x8  __attribute__((ext_vector_type(8)));

__device__ __forceinline__ void gload_lds16(const void* g, void* l) {
  __builtin_amdgcn_global_load_lds(
      (const __attribute__((address_space(1))) void*)g,
      (__attribute__((address_space(3))) void*)l, 16, 0, 0);
}

// ---------- kernel 1: row-L2-normalize -> fp8 e4m3 (x64), exact fp32 diagonal ----------
__global__ __launch_bounds__(256) void nrm_kernel(
    const float* __restrict__ e1, const float* __restrict__ e2,
    uint32_t* __restrict__ e1q, uint32_t* __restrict__ e2q,
    float* __restrict__ log_diag, float* __restrict__ exp_diag,
    float* __restrict__ row_sum, float* __restrict__ col_sum)
{
  const int row  = blockIdx.x;
  const int tid  = threadIdx.x;
  const int lane = tid & 63;
  const int wave = tid >> 6;
  const int64_t base = (int64_t)row * DD;

  const float4 v1 = *reinterpret_cast<const float4*>(e1 + base + tid * 4);
  const float4 v2 = *reinterpret_cast<const float4*>(e2 + base + tid * 4);

  float ss1 = v1.x*v1.x + v1.y*v1.y + v1.z*v1.z + v1.w*v1.w;
  float ss2 = v2.x*v2.x + v2.y*v2.y + v2.z*v2.z + v2.w*v2.w;
  float d12 = v1.x*v2.x + v1.y*v2.y + v1.z*v2.z + v1.w*v2.w;

  #pragma unroll
  for (int off = 1; off < 64; off <<= 1) {
    ss1 += __shfl_xor(ss1, off);
    ss2 += __shfl_xor(ss2, off);
    d12 += __shfl_xor(d12, off);
  }

  __shared__ float red[3][4];
  if (lane == 0) { red[0][wave] = ss1; red[1][wave] = ss2; red[2][wave] = d12; }
  __syncthreads();
  ss1 = red[0][0] + red[0][1] + red[0][2] + red[0][3];
  ss2 = red[1][0] + red[1][1] + red[1][2] + red[1][3];
  d12 = red[2][0] + red[2][1] + red[2][2] + red[2][3];

  const float inv1 = 1.0f / fmaxf(sqrtf(ss1), 1e-12f);
  const float inv2 = 1.0f / fmaxf(sqrtf(ss2), 1e-12f);

  if (tid == 0) {
    const float ld = d12 * inv1 * inv2 * 10.0f;
    log_diag[row] = ld;
    exp_diag[row] = __expf(ld);
    row_sum[row] = 0.0f;
    col_sum[row] = 0.0f;
  }

  const float s1 = inv1 * 64.0f;
  const float s2 = inv2 * 64.0f;
  int u1 = __builtin_amdgcn_cvt_pk_fp8_f32(v1.x * s1, v1.y * s1, 0, false);
  u1     = __builtin_amdgcn_cvt_pk_fp8_f32(v1.z * s1, v1.w * s1, u1, true);
  int u2 = __builtin_amdgcn_cvt_pk_fp8_f32(v2.x * s2, v2.y * s2, 0, false);
  u2     = __builtin_amdgcn_cvt_pk_fp8_f32(v2.z * s2, v2.w * s2, u2, true);
  e1q[row * (DD / 4) + tid] = (uint32_t)u1;
  e2q[row * (DD / 4) + tid] = (uint32_t)u2;
}

// ---------- kernel 2: fused MX-fp8 GEMM, 128x128 tile, 4 waves, 3 blocks/CU ----------
// Same verified MX math/swizzle as R7/R8 (absmax 0.0), but 256-thread blocks
// with __launch_bounds__(256,3): unified-reg cap 170 (was 128 -> acc spilled
// to scratch, 300 MB traffic). 4 waves (2M x 2N), wave tile 64x64,
// mfma_scale_f32_32x32x64_f8f6f4, scales = 0x7F (1.0). LDS 32 KiB dbuf.
__global__ __launch_bounds__(256, 3) void gemm_kernel(
    const uint8_t* __restrict__ A,   // e1q [NN][DD] fp8 bits (x64)
    const uint8_t* __restrict__ B,   // e2q [NN][DD] fp8 bits (x64)
    float* __restrict__ row_sum, float* __restrict__ col_sum)
{
  __shared__ __align__(16) uint8_t lds_a[2][128][64];   // 16 KiB
  __shared__ __align__(16) uint8_t lds_b[2][128][64];   // 16 KiB

  const int tid  = threadIdx.x;
  const int lane = tid & 63;
  const int wave = tid >> 6;          // 0..3
  const int wm = wave >> 1;           // 0..1 : rows [wm*64, +64)
  const int wn = wave & 1;            // 0..1 : cols [wn*64, +64)

  // XCD swizzle: grid 32x32 tiles; each XCD owns an 8x16 rectangle
  // (A 1 MB + B 2 MB = 3 MB < 4 MB per-XCD L2). 1024 % 8 == 0 -> bijective.
  const int bid = blockIdx.x;
  const int xcd = bid & 7;
  const int k   = bid >> 3;           // 0..127
  const int brow = ((xcd >> 1) * 8 + (k >> 4)) * 128;
  const int bcol = ((xcd & 1) * 16 + (k & 15)) * 128;

  // fragment geometry (32x32x64): row = lane&31, k = (lane>>5)*32 + e
  const int r32 = lane & 31;
  const int h   = lane >> 5;
  const int cx  = (r32 >> 1) & 3;               // row-derived 16B-chunk XOR
  const int ch0 = ((h * 2)     ^ cx) * 16;      // byte offset, first 16B of frag
  const int ch1 = ((h * 2 + 1) ^ cx) * 16;      // second 16B

  // staging: lane l writes 16B chunk (l&3) of row (l>>2); source chunk
  // pre-swizzled by ((row>>1)&3) = ((l>>3)&3)  [same involution as read side]
  const int s_chunk = ((lane & 3) ^ ((lane >> 3) & 3)) * 16;
  const int s_row   = wave * 32 + (lane >> 2);
  const uint8_t* a_src0 = A + (int64_t)(brow + s_row) * DD + s_chunk;
  const uint8_t* a_src1 = a_src0 + 16 * DD;
  const uint8_t* b_src0 = B + (int64_t)(bcol + s_row) * DD + s_chunk;
  const uint8_t* b_src1 = b_src0 + 16 * DD;

  f32x16 acc00 = {}, acc01 = {}, acc10 = {}, acc11 = {};

#define STAGE(n, kc)                                          \
  gload_lds16(a_src0 + (kc), &lds_a[n][wave * 32][0]);        \
  gload_lds16(a_src1 + (kc), &lds_a[n][wave * 32 + 16][0]);   \
  gload_lds16(b_src0 + (kc), &lds_b[n][wave * 32][0]);        \
  gload_lds16(b_src1 + (kc), &lds_b[n][wave * 32 + 16][0]);

#define LOADFRAG(dst, ldsbuf, c, rbase)                                        \
  {                                                                            \
    const i32x4 lo_ = *reinterpret_cast<const i32x4*>(&ldsbuf[c][rbase][ch0]); \
    const i32x4 hi_ = *reinterpret_cast<const i32x4*>(&ldsbuf[c][rbase][ch1]); \
    dst = __builtin_shufflevector(lo_, hi_, 0, 1, 2, 3, 4, 5, 6, 7);           \
  }

#define TILE(c, PF, KC)                                                        \
  {                                                                            \
    asm volatile("s_waitcnt vmcnt(0)" ::: "memory");                           \
    __builtin_amdgcn_s_barrier();                                              \
    i32x8 av0, av1, bv0, bv1;                                                  \
    LOADFRAG(av0, lds_a, c, wm * 64 + r32)                                     \
    LOADFRAG(av1, lds_a, c, wm * 64 + 32 + r32)                                \
    LOADFRAG(bv0, lds_b, c, wn * 64 + r32)                                     \
    LOADFRAG(bv1, lds_b, c, wn * 64 + 32 + r32)                                \
    if (PF) { STAGE((c) ^ 1, KC) }                                             \
    __builtin_amdgcn_s_setprio(1);                                             \
    acc00 = __builtin_amdgcn_mfma_scale_f32_32x32x64_f8f6f4(                   \
        av0, bv0, acc00, 0, 0, 0, 0x7F7F7F7F, 0, 0x7F7F7F7F);                  \
    acc01 = __builtin_amdgcn_mfma_scale_f32_32x32x64_f8f6f4(                   \
        av0, bv1, acc01, 0, 0, 0, 0x7F7F7F7F, 0, 0x7F7F7F7F);                  \
    acc10 = __builtin_amdgcn_mfma_scale_f32_32x32x64_f8f6f4(                   \
        av1, bv0, acc10, 0, 0, 0, 0x7F7F7F7F, 0, 0x7F7F7F7F);                  \
    acc11 = __builtin_amdgcn_mfma_scale_f32_32x32x64_f8f6f4(                   \
        av1, bv1, acc11, 0, 0, 0, 0x7F7F7F7F, 0, 0x7F7F7F7F);                  \
    __builtin_amdgcn_s_setprio(0);                                             \
  }

  // prologue: stage tile 0 into slot 0
  STAGE(0, 0)

  #pragma unroll 2
  for (int t = 0; t < DD / 64; ++t) {
    TILE(t & 1, t < DD / 64 - 1, (t + 1) * 64)
  }
#undef TILE
#undef LOADFRAG
#undef STAGE

  // ---- fused epilogue: v = exp(SCL*acc); row & col partial sums ----
  // 32x32 C/D layout: col = lane&31, row = (r&3) + 8*(r>>2) + 4*(lane>>5)
  float colp0 = 0.0f, colp1 = 0.0f;

#define ROWSUM(ACCL, ACCR, MI)                                                 \
  {                                                                            \
    _Pragma("unroll")                                                          \
    for (int r = 0; r < 16; ++r) {                                             \
      const float vL = __expf((ACCL)[r] * SCL);                                \
      const float vR = __expf((ACCR)[r] * SCL);                                \
      colp0 += vL;                                                             \
      colp1 += vR;                                                             \
      float rr = vL + vR;                                                      \
      rr += __shfl_xor(rr, 1);                                                 \
      rr += __shfl_xor(rr, 2);                                                 \
      rr += __shfl_xor(rr, 4);                                                 \
      rr += __shfl_xor(rr, 8);                                                 \
      rr += __shfl_xor(rr, 16);                                                \
      if (r32 == 0) {                                                          \
        atomicAdd(&row_sum[brow + wm * 64 + (MI) * 32 +                        \
                           (r & 3) + 8 * (r >> 2) + 4 * h], rr);               \
      }                                                                        \
    }                                                                          \
  }

  ROWSUM(acc00, acc01, 0)
  ROWSUM(acc10, acc11, 1)
#undef ROWSUM

  // col sums: combine the two 32-lane halves (same col, disjoint rows)
  {
    float cc = colp0;
    cc += __shfl_xor(cc, 32);
    if (h == 0) atomicAdd(&col_sum[bcol + wn * 64 + r32], cc);
  }
  {
    float cc = colp1;
    cc += __shfl_xor(cc, 32);
    if (h == 0) atomicAdd(&col_sum[bcol + wn * 64 + 32 + r32], cc);
  }
}

// ---------- kernel 3: final scalar reduction (block 0 -> rows, block 1 -> cols) ----------
__global__ __launch_bounds__(1024) void fin_kernel(
    const float* __restrict__ row_sum, const float* __restrict__ col_sum,
    const float* __restrict__ log_diag, const float* __restrict__ exp_diag,
    float* __restrict__ out)
{
  const int tid  = threadIdx.x;
  const int lane = tid & 63;
  const int wave = tid >> 6;
  const float* sums = (blockIdx.x == 0) ? row_sum : col_sum;
  float a = 0.0f;
  #pragma unroll
  for (int kk = 0; kk < NN / 1024; ++kk) {
    const int i = tid + kk * 1024;
    a += logf(sums[i] - exp_diag[i]) - log_diag[i];
  }
  #pragma unroll
  for (int off = 1; off < 64; off <<= 1) a += __shfl_xor(a, off);
  __shared__ float r0[16];
  if (lane == 0) r0[wave] = a;
  __syncthreads();
  if (tid == 0) {
    float s = 0.0f;
    #pragma unroll
    for (int w = 0; w < 16; ++w) s += r0[w];
    out[blockIdx.x] = s;
  }
}

extern "C" void kernel_launch(void* const* d_in, const int* in_sizes, int n_in,
                              void* d_out, int out_size, void* d_ws, size_t ws_size,
                              hipStream_t stream) {
  const float* e1 = (const float*)d_in[0];
  const float* e2 = (const float*)d_in[1];
  float* out = (float*)d_out;

  char* ws = (char*)d_ws;
  uint32_t* e1q = (uint32_t*)ws;                                 // 4 MB (fp8)
  uint32_t* e2q = (uint32_t*)(ws + (size_t)NN * DD);             // 4 MB (fp8)
  float* log_diag = (float*)(ws + (size_t)NN * DD * 2);          // 16 KB
  float* exp_diag = log_diag + NN;                               // 16 KB
  float* row_sum  = exp_diag + NN;                               // 16 KB
  float* col_sum  = row_sum + NN;                                // 16 KB

  nrm_kernel<<<NN, 256, 0, stream>>>(e1, e2, e1q, e2q, log_diag, exp_diag,
                                     row_sum, col_sum);
  gemm_kernel<<<1024, 256, 0, stream>>>((const uint8_t*)e1q, (const uint8_t*)e2q,
                                        row_sum, col_sum);
  fin_kernel<<<2, 1024, 0, stream>>>(row_sum, col_sum, log_diag, exp_diag, out);
}